// Round 5
// baseline (516.343 us; speedup 1.0000x reference)
//
#include <hip/hip_runtime.h>

#define NNODES 1700
#define CDIM   256
#define NB     64  // batch (fixed: in_sizes[0] = 64*1700*256)

typedef __attribute__((ext_vector_type(8))) short bf16x8;
typedef __attribute__((ext_vector_type(4))) float f32x4;

__device__ inline float bf2f(unsigned h) { return __uint_as_float(h << 16); }
__device__ inline unsigned short f2bf(float f) {
  unsigned u = __float_as_uint(f);
  u = (u + 0x7FFFu + ((u >> 16) & 1u)) >> 16;  // RNE
  return (unsigned short)u;
}

__device__ inline void async_copy16(const void* gsrc, void* ldst) {
  __builtin_amdgcn_global_load_lds(
      (const __attribute__((address_space(1))) unsigned int*)gsrc,
      (__attribute__((address_space(3))) unsigned int*)ldst,
      16, 0, 0);
}

// ---------------- graph preprocessing ----------------

__global__ void zero_kernel(int* p, int n) {
  int i = blockIdx.x * blockDim.x + threadIdx.x;
  if (i < n) p[i] = 0;
}

__global__ void count_kernel(const int* __restrict__ ei, int E, int* __restrict__ cnt) {
  int i = blockIdx.x * blockDim.x + threadIdx.x;
  if (i < E) atomicAdd(&cnt[ei[E + i]], 1);
}

__global__ void dinv_kernel(const int* __restrict__ cnt, float* __restrict__ dinv, int n) {
  int i = blockIdx.x * blockDim.x + threadIdx.x;
  if (i < n) dinv[i] = rsqrtf((float)(cnt[i] + 1));
}

__global__ __launch_bounds__(1024) void scan_kernel(const int* __restrict__ cnt, int n,
                                                    int* __restrict__ off) {
  __shared__ int s[2048];
  int t = threadIdx.x;
  for (int i = t; i < 2048; i += 1024) s[i] = (i < n) ? (cnt[i] + 1) : 0;
  for (int d = 1; d < 2048; d <<= 1) {
    __syncthreads();
    int idx = (t + 1) * (d << 1) - 1;
    if (idx < 2048) s[idx] += s[idx - d];
  }
  __syncthreads();
  if (t == 0) s[2047] = 0;
  for (int d = 1024; d >= 1; d >>= 1) {
    __syncthreads();
    int idx = (t + 1) * (d << 1) - 1;
    if (idx < 2048) { int tmp = s[idx - d]; s[idx - d] = s[idx]; s[idx] += tmp; }
  }
  __syncthreads();
  for (int i = t; i <= n; i += 1024) off[i] = s[i];
}

__global__ void fill_kernel(const int* __restrict__ ei, int E, int n,
                            const float* __restrict__ dinv, const int* __restrict__ off,
                            int* __restrict__ cursor, int* __restrict__ srcv,
                            float* __restrict__ wv) {
  int i = blockIdx.x * blockDim.x + threadIdx.x;
  if (i >= E + n) return;
  int s, d;
  if (i < E) { s = ei[i]; d = ei[E + i]; } else { s = d = i - E; }
  float w = dinv[s] * dinv[d];
  int p = atomicAdd(&cursor[d], 1);
  int idx = off[d] + p;
  srcv[idx] = s;
  wv[idx] = w;
}

// W f32 [k][n] -> Wtt bf16 K-tiled [s][n][32]  (s = k/32)
__global__ void transpose_kernel(const float* __restrict__ W,
                                 unsigned short* __restrict__ Wtt) {
  int i = blockIdx.x * 256 + threadIdx.x;
  int k = i >> 8, n = i & 255;
  Wtt[(((k >> 5) << 8) + n) * 32 + (k & 31)] = f2bf(W[i]);
}

// ---------------- GEMM: H[m][256] = A[m][256] @ W, 64-row x full-N tile ----------------
// Block = 64 rows x 256 cols, 32 KB LDS, 12 waves/CU target. A-tile [s][row][32] staged
// up-front, ONE barrier, fully-unrolled K loop; B-frags direct from L2-resident Wtt.
// Wave-tile 32 rows x 128 cols (acc[2][8]). WIDE: LDS-repack epilogue -> dwordx4 stores.

template <bool AF32, bool WIDE>
__global__ __launch_bounds__(256, 3) void gemm_fullN(const void* __restrict__ Ap,
                                                     const unsigned short* __restrict__ Wtt,
                                                     unsigned short* __restrict__ H) {
  __shared__ __align__(16) unsigned short As[8 * 64 * 32];  // 32 KB
  const int t = threadIdx.x;
  const int row0 = blockIdx.x * 64;

  if (AF32) {
    const float* A = (const float*)Ap;
#pragma unroll
    for (int j = 0; j < 8; j++) {
      const int c = t + j * 256;                       // 16B-LDS-chunk id (= 32B f32)
      const int u = c & 3, row = (c >> 2) & 63, s = c >> 8;
      const int g = row0 + row;
      const int n = g >> 6, b = g & (NB - 1);          // m = n*64 + b
      const float* src = A + ((size_t)b * NNODES + n) * CDIM + s * 32 + u * 8;
      float4 f0 = *(const float4*)src;
      float4 f1 = *(const float4*)(src + 4);
      bf16x8 pk;
      pk[0] = (short)f2bf(f0.x); pk[1] = (short)f2bf(f0.y);
      pk[2] = (short)f2bf(f0.z); pk[3] = (short)f2bf(f0.w);
      pk[4] = (short)f2bf(f1.x); pk[5] = (short)f2bf(f1.y);
      pk[6] = (short)f2bf(f1.z); pk[7] = (short)f2bf(f1.w);
      *(bf16x8*)((char*)As + (size_t)c * 16) = pk;
    }
  } else {
    const unsigned short* A = (const unsigned short*)Ap;
#pragma unroll
    for (int j = 0; j < 8; j++) {
      const int c = t + j * 256;
      const int u = c & 3, row = (c >> 2) & 63, s = c >> 8;
      async_copy16(A + (size_t)(row0 + row) * CDIM + s * 32 + u * 8,
                   (char*)As + (size_t)c * 16);
    }
  }
  __syncthreads();

  const int lane = t & 63, w = t >> 6;
  const int wm = (w & 1) * 32, wn = (w >> 1) * 128;
  const int rl = lane & 15, q = lane >> 4;
  f32x4 acc[2][8];
#pragma unroll
  for (int mi = 0; mi < 2; mi++)
#pragma unroll
    for (int ni = 0; ni < 8; ni++) acc[mi][ni] = (f32x4){0.f, 0.f, 0.f, 0.f};

#pragma unroll
  for (int s = 0; s < 8; s++) {
    bf16x8 a[2];
#pragma unroll
    for (int mi = 0; mi < 2; mi++)
      a[mi] = *(const bf16x8*)((char*)As + s * 4096 + (wm + mi * 16 + rl) * 64 + q * 16);
#pragma unroll
    for (int ni = 0; ni < 8; ni++) {
      bf16x8 bfr = *(const bf16x8*)&Wtt[((s << 8) + wn + ni * 16 + rl) * 32 + (q << 3)];
#pragma unroll
      for (int mi = 0; mi < 2; mi++)
        acc[mi][ni] = __builtin_amdgcn_mfma_f32_16x16x32_bf16(a[mi], bfr, acc[mi][ni], 0, 0, 0);
    }
  }

  const int orow = q * 4;  // C/D: col=lane&15, row=(lane>>4)*4+rr
  if (WIDE) {
    // repack through LDS -> 16B coalesced stores
    __syncthreads();  // all waves done reading As
    unsigned short* Cs = As;  // bf16 [64][256]
#pragma unroll
    for (int mi = 0; mi < 2; mi++)
#pragma unroll
      for (int ni = 0; ni < 8; ni++) {
        const int col = wn + ni * 16 + rl;
#pragma unroll
        for (int rr = 0; rr < 4; rr++)
          Cs[(wm + mi * 16 + orow + rr) * 256 + col] = f2bf(acc[mi][ni][rr]);
      }
    __syncthreads();
#pragma unroll
    for (int j = 0; j < 8; j++) {
      const int c = t + j * 256;          // 16B chunk: row = c>>5, colu = c&31
      const int row = c >> 5, colu = c & 31;
      uint4 v = *(const uint4*)((char*)Cs + (size_t)c * 16);
      *(uint4*)(H + (size_t)(row0 + row) * CDIM + colu * 8) = v;
    }
  } else {
#pragma unroll
    for (int mi = 0; mi < 2; mi++) {
#pragma unroll
      for (int ni = 0; ni < 8; ni++) {
        const int col = wn + ni * 16 + rl;
#pragma unroll
        for (int rr = 0; rr < 4; rr++) {
          const int grow = row0 + wm + mi * 16 + orow + rr;
          H[(size_t)grow * CDIM + col] = f2bf(acc[mi][ni][rr]);
        }
      }
    }
  }
}

// ---------------- aggregation: per (node, 4 batches) block ----------------

template <bool FINAL>
__global__ __launch_bounds__(256) void agg_kernel(const unsigned short* __restrict__ H,
                                                  const int* __restrict__ off,
                                                  const int* __restrict__ srcv,
                                                  const float* __restrict__ wv,
                                                  const float* __restrict__ bias,
                                                  const float* __restrict__ resid,
                                                  void* __restrict__ outp) {
  const int n = blockIdx.x;
  const int b = blockIdx.y * 4 + (threadIdx.x >> 6);
  const int c = (threadIdx.x & 63) * 4;
  const int beg = off[n], end = off[n + 1];
  const unsigned short* Hb = H + (size_t)b * CDIM + c;

  float a0 = 0.f, a1 = 0.f, a2 = 0.f, a3 = 0.f;
  int sr = srcv[beg];
  float w = wv[beg];
  uint2 v = *(const uint2*)(Hb + (size_t)sr * (NB * CDIM));
  for (int e = beg + 1; e < end; e++) {
    int sr1 = srcv[e];
    float w1 = wv[e];
    uint2 v1 = *(const uint2*)(Hb + (size_t)sr1 * (NB * CDIM));
    a0 += w * bf2f(v.x & 0xffffu);
    a1 += w * bf2f(v.x >> 16);
    a2 += w * bf2f(v.y & 0xffffu);
    a3 += w * bf2f(v.y >> 16);
    w = w1; v = v1;
  }
  a0 += w * bf2f(v.x & 0xffffu);
  a1 += w * bf2f(v.x >> 16);
  a2 += w * bf2f(v.y & 0xffffu);
  a3 += w * bf2f(v.y >> 16);

  float4 bv = *(const float4*)(bias + c);
  a0 += bv.x; a1 += bv.y; a2 += bv.z; a3 += bv.w;

  if (FINAL) {
    const size_t o = ((size_t)b * NNODES + n) * CDIM + c;  // [b][n][c] f32
    float4 rv = *(const float4*)(resid + o);
    a0 = fmaxf(a0 + rv.x, 0.f); a1 = fmaxf(a1 + rv.y, 0.f);
    a2 = fmaxf(a2 + rv.z, 0.f); a3 = fmaxf(a3 + rv.w, 0.f);
    float4 ov; ov.x = a0; ov.y = a1; ov.z = a2; ov.w = a3;
    *(float4*)((float*)outp + o) = ov;
  } else {
    const size_t o = ((size_t)n * NB + b) * CDIM + c;      // [n][b][c] bf16
    a0 = fmaxf(a0, 0.f); a1 = fmaxf(a1, 0.f); a2 = fmaxf(a2, 0.f); a3 = fmaxf(a3, 0.f);
    uint2 ov;
    ov.x = (unsigned)f2bf(a0) | ((unsigned)f2bf(a1) << 16);
    ov.y = (unsigned)f2bf(a2) | ((unsigned)f2bf(a3) << 16);
    *(uint2*)((unsigned short*)outp + o) = ov;
  }
}

// ---------------- launch ----------------

extern "C" void kernel_launch(void* const* d_in, const int* in_sizes, int n_in,
                              void* d_out, int out_size, void* d_ws, size_t ws_size,
                              hipStream_t stream) {
  const float* x  = (const float*)d_in[0];
  const float* W1 = (const float*)d_in[1];
  const float* b1 = (const float*)d_in[2];
  const float* W2 = (const float*)d_in[3];
  const float* b2 = (const float*)d_in[4];
  const float* W3 = (const float*)d_in[5];
  const float* b3 = (const float*)d_in[6];
  const int* esp = (const int*)d_in[7];
  const int* etm = (const int*)d_in[8];

  const int Esp = in_sizes[7] / 2;
  const int Etm = in_sizes[8] / 2;
  const int M = NB * NNODES;  // 108800

  char* ws = (char*)d_ws;
  size_t woff = 0;
  auto alloc = [&](size_t bytes) -> void* {
    void* p = ws + woff;
    woff = (woff + bytes + 255) & ~(size_t)255;
    return p;
  };

  unsigned short* H   = (unsigned short*)alloc((size_t)M * CDIM * 2);
  unsigned short* Act = (unsigned short*)alloc((size_t)M * CDIM * 2);
  unsigned short* Wtt = (unsigned short*)alloc((size_t)3 * CDIM * CDIM * 2);
  int* zero_base = (int*)alloc((size_t)4 * NNODES * sizeof(int));
  int* cnt_sp = zero_base;
  int* cur_sp = zero_base + NNODES;
  int* cnt_tm = zero_base + 2 * NNODES;
  int* cur_tm = zero_base + 3 * NNODES;
  int* off_sp = (int*)alloc((NNODES + 1) * sizeof(int));
  int* off_tm = (int*)alloc((NNODES + 1) * sizeof(int));
  float* dinv_sp = (float*)alloc(NNODES * sizeof(float));
  float* dinv_tm = (float*)alloc(NNODES * sizeof(float));
  int*   src_sp = (int*)alloc((size_t)(Esp + NNODES) * sizeof(int));
  float* wgt_sp = (float*)alloc((size_t)(Esp + NNODES) * sizeof(float));
  int*   src_tm = (int*)alloc((size_t)(Etm + NNODES) * sizeof(int));
  float* wgt_tm = (float*)alloc((size_t)(Etm + NNODES) * sizeof(float));

  zero_kernel<<<(4 * NNODES + 255) / 256, 256, 0, stream>>>(zero_base, 4 * NNODES);
  transpose_kernel<<<256, 256, 0, stream>>>(W1, Wtt);
  transpose_kernel<<<256, 256, 0, stream>>>(W2, Wtt + CDIM * CDIM);
  transpose_kernel<<<256, 256, 0, stream>>>(W3, Wtt + 2 * CDIM * CDIM);
  count_kernel<<<(Esp + 255) / 256, 256, 0, stream>>>(esp, Esp, cnt_sp);
  count_kernel<<<(Etm + 255) / 256, 256, 0, stream>>>(etm, Etm, cnt_tm);
  dinv_kernel<<<(NNODES + 255) / 256, 256, 0, stream>>>(cnt_sp, dinv_sp, NNODES);
  dinv_kernel<<<(NNODES + 255) / 256, 256, 0, stream>>>(cnt_tm, dinv_tm, NNODES);
  scan_kernel<<<1, 1024, 0, stream>>>(cnt_sp, NNODES, off_sp);
  scan_kernel<<<1, 1024, 0, stream>>>(cnt_tm, NNODES, off_tm);
  fill_kernel<<<(Esp + NNODES + 255) / 256, 256, 0, stream>>>(esp, Esp, NNODES, dinv_sp,
                                                              off_sp, cur_sp, src_sp, wgt_sp);
  fill_kernel<<<(Etm + NNODES + 255) / 256, 256, 0, stream>>>(etm, Etm, NNODES, dinv_tm,
                                                              off_tm, cur_tm, src_tm, wgt_tm);

  const int nblk = M / 64;  // 1700
  dim3 agrid(NNODES, NB / 4);

  // layer 1 (spatial): scalar-store epilogue
  gemm_fullN<true, false><<<nblk, 256, 0, stream>>>(x, Wtt, H);
  agg_kernel<false><<<agrid, 256, 0, stream>>>(H, off_sp, src_sp, wgt_sp, b1, nullptr, Act);
  // layer 2 (temporal): scalar-store epilogue  (A-side of in-launch store A/B)
  gemm_fullN<false, false><<<nblk, 256, 0, stream>>>(Act, Wtt + CDIM * CDIM, H);
  agg_kernel<false><<<agrid, 256, 0, stream>>>(H, off_tm, src_tm, wgt_tm, b2, nullptr, Act);
  // layer 3 (spatial): WIDE LDS-repack epilogue (B-side of store A/B)
  gemm_fullN<false, true><<<nblk, 256, 0, stream>>>(Act, Wtt + 2 * CDIM * CDIM, H);
  agg_kernel<true><<<agrid, 256, 0, stream>>>(H, off_sp, src_sp, wgt_sp, b3, x, d_out);
}